// Round 1
// baseline (135.169 us; speedup 1.0000x reference)
//
#include <hip/hip_runtime.h>

typedef __attribute__((ext_vector_type(8))) short bf16x8;
typedef __attribute__((ext_vector_type(4))) float f32x4;

#define LSTRIDE 72   // 64 + 8 pad (keeps 16B alignment, breaks bank aliasing)
#define DHEAD   64
#define L_SEQ   2048

__device__ __forceinline__ ushort f2bf(float f) {
    union { float f; unsigned int u; } v; v.f = f;
    return (ushort)((v.u + 0x7FFFu + ((v.u >> 16) & 1u)) >> 16);  // RNE
}
__device__ __forceinline__ unsigned int pack2(float a, float b) {
    return (unsigned int)f2bf(a) | ((unsigned int)f2bf(b) << 16);
}

__global__ __launch_bounds__(256, 4)
void fattn_kernel(const float* __restrict__ Qg, const float* __restrict__ Kg,
                  const float* __restrict__ Vg, float* __restrict__ Og) {
    __shared__ ushort sQ[64 * LSTRIDE];
    __shared__ ushort sK[64 * LSTRIDE];
    __shared__ ushort sVt[64 * LSTRIDE];   // transposed V: [d][k^swz]
    __shared__ ushort sP[64 * LSTRIDE];    // 4 waves x 16 rows, wave-private

    const int tid  = threadIdx.x;
    const int lane = tid & 63;
    const int w    = tid >> 6;     // wave 0..3 -> q rows w*16..w*16+15
    const int g    = lane >> 4;    // 4-row group within C/D layout
    const int c    = lane & 15;    // column within 16

    // load-balance: pair light/heavy q-tiles so co-resident blocks have equal work
    const int bid = blockIdx.x;
    const int qt  = (bid & 1) ? (31 - (bid >> 1)) : (bid >> 1);
    const size_t base = (size_t)blockIdx.y * L_SEQ * DHEAD;

    const float* Qp = Qg + base + (size_t)qt * 64 * DHEAD;
    float*       Op = Og + base + (size_t)qt * 64 * DHEAD;

    // ---- stage Q tile (64x64 f32 -> bf16 LDS, row-major) ----
    {
        int row = tid >> 2, c0 = (tid & 3) * 16;
        const float4* s4 = (const float4*)(Qp + row * DHEAD + c0);
        float4 f0 = s4[0], f1 = s4[1], f2 = s4[2], f3 = s4[3];
        uint4 p0, p1;
        p0.x = pack2(f0.x, f0.y); p0.y = pack2(f0.z, f0.w);
        p0.z = pack2(f1.x, f1.y); p0.w = pack2(f1.z, f1.w);
        p1.x = pack2(f2.x, f2.y); p1.y = pack2(f2.z, f2.w);
        p1.z = pack2(f3.x, f3.y); p1.w = pack2(f3.z, f3.w);
        *(uint4*)&sQ[row * LSTRIDE + c0]     = p0;
        *(uint4*)&sQ[row * LSTRIDE + c0 + 8] = p1;
    }
    __syncthreads();
    // Q A-fragments, hoisted: row = c, k-chunk = kc*32 + g*8 .. +7
    const bf16x8 qa0 = *(const bf16x8*)&sQ[(w * 16 + c) * LSTRIDE + g * 8];
    const bf16x8 qa1 = *(const bf16x8*)&sQ[(w * 16 + c) * LSTRIDE + 32 + g * 8];

    f32x4 o[4];
    f32x4 zero = {0.f, 0.f, 0.f, 0.f};
    o[0] = zero; o[1] = zero; o[2] = zero; o[3] = zero;
    float m_r[4] = {-INFINITY, -INFINITY, -INFINITY, -INFINITY};
    float l_r[4] = {0.f, 0.f, 0.f, 0.f};

    const int nt = qt + 1;   // causal: kv tiles 0..qt
    for (int kt = 0; kt < nt; ++kt) {
        const float* Kp = Kg + base + (size_t)kt * 64 * DHEAD;
        const float* Vp = Vg + base + (size_t)kt * 64 * DHEAD;

        __syncthreads();   // previous tile's K/V reads complete
        {   // stage K (row-major bf16)
            int row = tid >> 2, c0 = (tid & 3) * 16;
            const float4* s4 = (const float4*)(Kp + row * DHEAD + c0);
            float4 f0 = s4[0], f1 = s4[1], f2 = s4[2], f3 = s4[3];
            uint4 p0, p1;
            p0.x = pack2(f0.x, f0.y); p0.y = pack2(f0.z, f0.w);
            p0.z = pack2(f1.x, f1.y); p0.w = pack2(f1.z, f1.w);
            p1.x = pack2(f2.x, f2.y); p1.y = pack2(f2.z, f2.w);
            p1.z = pack2(f3.x, f3.y); p1.w = pack2(f3.z, f3.w);
            *(uint4*)&sK[row * LSTRIDE + c0]     = p0;
            *(uint4*)&sK[row * LSTRIDE + c0 + 8] = p1;
        }
        {   // stage V transposed: sVt[d][k'] with k-block XOR swizzle on (d>>3)
            int kr = (tid >> 3) * 2;       // even key row
            int d0 = (tid & 7) * 8;
            const float4* r0 = (const float4*)(Vp + kr * DHEAD + d0);
            const float4* r1 = (const float4*)(Vp + (kr + 1) * DHEAD + d0);
            float4 a0 = r0[0], a1 = r0[1];
            float4 b0 = r1[0], b1 = r1[1];
            float va[8] = {a0.x, a0.y, a0.z, a0.w, a1.x, a1.y, a1.z, a1.w};
            float vb[8] = {b0.x, b0.y, b0.z, b0.w, b1.x, b1.y, b1.z, b1.w};
            int kblk = kr >> 3;
            #pragma unroll
            for (int j = 0; j < 8; ++j) {
                int d = d0 + j;
                int kswz = (((kblk ^ (d >> 3)) & 7) << 3) | (kr & 7);
                *(unsigned int*)&sVt[d * LSTRIDE + kswz] = pack2(va[j], vb[j]);
            }
        }
        __syncthreads();

        // ---- S = Q K^T (16x64 per wave, 8 MFMAs) ----
        f32x4 sa[4];
        sa[0] = zero; sa[1] = zero; sa[2] = zero; sa[3] = zero;
        #pragma unroll
        for (int t = 0; t < 4; ++t) {
            bf16x8 bk0 = *(const bf16x8*)&sK[(t * 16 + c) * LSTRIDE + g * 8];
            sa[t] = __builtin_amdgcn_mfma_f32_16x16x32_bf16(qa0, bk0, sa[t], 0, 0, 0);
            bf16x8 bk1 = *(const bf16x8*)&sK[(t * 16 + c) * LSTRIDE + 32 + g * 8];
            sa[t] = __builtin_amdgcn_mfma_f32_16x16x32_bf16(qa1, bk1, sa[t], 0, 0, 0);
        }

        // ---- scale + causal mask ----
        float p[4][4];
        const bool diag = (kt == qt);
        #pragma unroll
        for (int t = 0; t < 4; ++t) {
            #pragma unroll
            for (int r = 0; r < 4; ++r) {
                float sv = sa[t][r] * 0.125f;
                if (diag && (t * 16 + c > w * 16 + g * 4 + r)) sv = -INFINITY;
                p[t][r] = sv;
            }
        }

        // ---- online softmax (wave-parallel, per q-row r) ----
        #pragma unroll
        for (int r = 0; r < 4; ++r) {
            float mx = fmaxf(fmaxf(p[0][r], p[1][r]), fmaxf(p[2][r], p[3][r]));
            mx = fmaxf(mx, __shfl_xor(mx, 1));
            mx = fmaxf(mx, __shfl_xor(mx, 2));
            mx = fmaxf(mx, __shfl_xor(mx, 4));
            mx = fmaxf(mx, __shfl_xor(mx, 8));
            float mn    = fmaxf(m_r[r], mx);
            float alpha = __expf(m_r[r] - mn);
            m_r[r] = mn;
            float rs = 0.f;
            #pragma unroll
            for (int t = 0; t < 4; ++t) { p[t][r] = __expf(p[t][r] - mn); rs += p[t][r]; }
            rs += __shfl_xor(rs, 1);
            rs += __shfl_xor(rs, 2);
            rs += __shfl_xor(rs, 4);
            rs += __shfl_xor(rs, 8);
            l_r[r] = l_r[r] * alpha + rs;
            #pragma unroll
            for (int dt = 0; dt < 4; ++dt) o[dt][r] *= alpha;
        }

        // ---- P -> bf16 LDS (wave-private slab; no barrier needed) ----
        #pragma unroll
        for (int t = 0; t < 4; ++t) {
            #pragma unroll
            for (int r = 0; r < 4; ++r)
                sP[(w * 16 + g * 4 + r) * LSTRIDE + t * 16 + c] = f2bf(p[t][r]);
        }

        // ---- O += P V  (8 MFMAs) ----
        #pragma unroll
        for (int kc = 0; kc < 2; ++kc) {
            bf16x8 ap = *(const bf16x8*)&sP[(w * 16 + c) * LSTRIDE + kc * 32 + g * 8];
            int kk = kc * 4 + g;   // k block index 0..7
            #pragma unroll
            for (int dt = 0; dt < 4; ++dt) {
                int d = dt * 16 + c;
                int kswz = ((kk ^ ((d >> 3) & 7)) << 3);
                bf16x8 bv = *(const bf16x8*)&sVt[d * LSTRIDE + kswz];
                o[dt] = __builtin_amdgcn_mfma_f32_16x16x32_bf16(ap, bv, o[dt], 0, 0, 0);
            }
        }
    }

    // ---- epilogue: O / l, fp32 out ----
    #pragma unroll
    for (int r = 0; r < 4; ++r) {
        float inv  = 1.f / l_r[r];
        int   qrow = w * 16 + g * 4 + r;
        #pragma unroll
        for (int dt = 0; dt < 4; ++dt)
            Op[qrow * DHEAD + dt * 16 + c] = o[dt][r] * inv;
    }
}

extern "C" void kernel_launch(void* const* d_in, const int* in_sizes, int n_in,
                              void* d_out, int out_size, void* d_ws, size_t ws_size,
                              hipStream_t stream) {
    const float* Q = (const float*)d_in[0];
    const float* K = (const float*)d_in[1];
    const float* V = (const float*)d_in[2];
    float* O = (float*)d_out;
    dim3 grid(32, 32);   // (q-tiles, B*H)
    fattn_kernel<<<grid, dim3(256), 0, stream>>>(Q, K, V, O);
}

// Round 2
// 79.218 us; speedup vs baseline: 1.7063x; 1.7063x over previous
//
#include <hip/hip_runtime.h>
#include <hip/hip_bf16.h>

typedef __attribute__((ext_vector_type(8))) short bf16x8;
typedef __attribute__((ext_vector_type(16))) float f32x16;

#define DHEAD 64
#define L_SEQ 2048

union U4S8 { uint4 u; bf16x8 s; };

__device__ __forceinline__ unsigned pk2(float a, float b) {
    union { __hip_bfloat162 h; unsigned u; } v;
    v.h = __float22bfloat162_rn(make_float2(a, b));
    return v.u;
}

// Layouts (per buffer):
//  K: 8 chunks (kb*4+kc), chunk = 64 x 16B; slot l holds K[kb*32+(l&31)][kc*16+8*(l>>5)+j]
//  V: 8 chunks (kc*2+dt), chunk = 65 x 16B (16B pad for write-bank spread);
//     slot l holds V[kc*16+8*(l>>5)+j][dt*32+(l&31)]
// => all MFMA fragment reads are ds_read_b128 at (chunk base + lane*16): conflict-free.

__global__ __launch_bounds__(128, 2)
void fattn_kernel(const float* __restrict__ Qg, const float* __restrict__ Kg,
                  const float* __restrict__ Vg, float* __restrict__ Og) {
    __shared__ uint4 sK4[2][8][64];
    __shared__ uint4 sV4[2][8][65];

    const int tid  = threadIdx.x;
    const int lane = tid & 63;
    const int w    = tid >> 6;     // wave 0..1 -> q rows w*32..w*32+31 of the 64-row tile
    const int hi   = lane >> 5;
    const int c    = lane & 31;

    // Block decode: XCD grouping (4 bh per XCD => K/V set ~= L2) + balanced causal qt map
    const int id  = blockIdx.x;
    const int xcd = id & 7;
    const int s_  = id >> 3;             // 0..127
    const int bh  = xcd + 8 * (s_ & 3);  // 0..31
    const int xr  = s_ >> 2;             // 0..31
    const int a_  = xr & 7, b_ = xr >> 3;
    const int qt  = (b_ & 1) ? (31 - (a_ * 2 + (b_ >> 1))) : (a_ * 2 + (b_ >> 1));

    const size_t base = (size_t)bh * L_SEQ * DHEAD;
    const int nt = qt + 1;               // causal kv tiles
    const int q0 = qt * 64 + w * 32;

    // ---- Q fragments (B-operand), softmax scale 1/8 folded in ----
    bf16x8 qf[4];
    {
        const float* Qrow = Qg + base + (size_t)(q0 + c) * DHEAD;
        #pragma unroll
        for (int kc = 0; kc < 4; ++kc) {
            float4 aa = *(const float4*)(Qrow + kc * 16 + hi * 8);
            float4 bb = *(const float4*)(Qrow + kc * 16 + hi * 8 + 4);
            U4S8 t;
            t.u = make_uint4(pk2(aa.x * 0.125f, aa.y * 0.125f),
                             pk2(aa.z * 0.125f, aa.w * 0.125f),
                             pk2(bb.x * 0.125f, bb.y * 0.125f),
                             pk2(bb.z * 0.125f, bb.w * 0.125f));
            qf[kc] = t.s;
        }
    }

    // staging thread mapping (128 threads)
    const int krow = tid >> 2;           // 0..31
    const int kcs  = tid & 3;            // K col segment (16 f32)
    const int koct = tid >> 4;           // 0..7  (V key octet)
    const int vd0  = (tid & 15) * 4;     // V d segment (4 f32)

    float4 rk[8], rv[8];

    auto load_tile = [&](int kt) {
        const float* Kp = Kg + base + (size_t)(kt * 64 + krow) * DHEAD + kcs * 16;
        rk[0] = *(const float4*)(Kp + 0);
        rk[1] = *(const float4*)(Kp + 4);
        rk[2] = *(const float4*)(Kp + 8);
        rk[3] = *(const float4*)(Kp + 12);
        const float* Kp2 = Kp + 32 * DHEAD;
        rk[4] = *(const float4*)(Kp2 + 0);
        rk[5] = *(const float4*)(Kp2 + 4);
        rk[6] = *(const float4*)(Kp2 + 8);
        rk[7] = *(const float4*)(Kp2 + 12);
        const float* Vp = Vg + base + (size_t)(kt * 64 + koct * 8) * DHEAD + vd0;
        #pragma unroll
        for (int i = 0; i < 8; ++i) rv[i] = *(const float4*)(Vp + (size_t)i * DHEAD);
    };

    auto write_tile = [&](int nb) {
        sK4[nb][kcs][krow]          = make_uint4(pk2(rk[0].x, rk[0].y), pk2(rk[0].z, rk[0].w),
                                                 pk2(rk[1].x, rk[1].y), pk2(rk[1].z, rk[1].w));
        sK4[nb][kcs][32 + krow]     = make_uint4(pk2(rk[2].x, rk[2].y), pk2(rk[2].z, rk[2].w),
                                                 pk2(rk[3].x, rk[3].y), pk2(rk[3].z, rk[3].w));
        sK4[nb][4 + kcs][krow]      = make_uint4(pk2(rk[4].x, rk[4].y), pk2(rk[4].z, rk[4].w),
                                                 pk2(rk[5].x, rk[5].y), pk2(rk[5].z, rk[5].w));
        sK4[nb][4 + kcs][32 + krow] = make_uint4(pk2(rk[6].x, rk[6].y), pk2(rk[6].z, rk[6].w),
                                                 pk2(rk[7].x, rk[7].y), pk2(rk[7].z, rk[7].w));
        #define VW(DJ, F) { const int d = vd0 + DJ;                                        \
            const int ch = ((koct >> 1) << 1) + (d >> 5);                                  \
            const int sl = ((koct & 1) << 5) | (d & 31);                                   \
            sV4[nb][ch][sl] = make_uint4(pk2(rv[0].F, rv[1].F), pk2(rv[2].F, rv[3].F),     \
                                         pk2(rv[4].F, rv[5].F), pk2(rv[6].F, rv[7].F)); }
        VW(0, x) VW(1, y) VW(2, z) VW(3, w)
        #undef VW
    };

    f32x16 o0 = {0,0,0,0,0,0,0,0,0,0,0,0,0,0,0,0};
    f32x16 o1 = {0,0,0,0,0,0,0,0,0,0,0,0,0,0,0,0};
    float m_r = -1e30f, l_r = 0.f;

    load_tile(0);
    write_tile(0);
    __syncthreads();

    for (int kt = 0; kt < nt; ++kt) {
        const int  cur = kt & 1;
        const bool pf  = (kt + 1 < nt);
        if (pf) load_tile(kt + 1);   // prefetch into regs; hides under compute

        // ---- S^T = K * Q^T : rows = keys (crow layout), cols = q = c ----
        f32x16 s0 = {0,0,0,0,0,0,0,0,0,0,0,0,0,0,0,0};
        f32x16 s1 = {0,0,0,0,0,0,0,0,0,0,0,0,0,0,0,0};
        #pragma unroll
        for (int kc = 0; kc < 4; ++kc) {
            U4S8 t0; t0.u = sK4[cur][kc][lane];
            s0 = __builtin_amdgcn_mfma_f32_32x32x16_bf16(t0.s, qf[kc], s0, 0, 0, 0);
        }
        #pragma unroll
        for (int kc = 0; kc < 4; ++kc) {
            U4S8 t1; t1.u = sK4[cur][4 + kc][lane];
            s1 = __builtin_amdgcn_mfma_f32_32x32x16_bf16(t1.s, qf[kc], s1, 0, 0, 0);
        }

        float p[2][16];
        #pragma unroll
        for (int r = 0; r < 16; ++r) { p[0][r] = s0[r]; p[1][r] = s1[r]; }

        if (kt == qt) {              // diagonal tile: causal mask
            const int qrel = w * 32 + c;
            #pragma unroll
            for (int r = 0; r < 16; ++r) {
                const int kk = (r & 3) + 8 * (r >> 2) + 4 * hi;
                if (kk > qrel)      p[0][r] = -1e30f;
                if (kk + 32 > qrel) p[1][r] = -1e30f;
            }
        }

        // ---- online softmax for q = q0 + c (in-lane 32 values + 1 cross-half) ----
        float mx = p[0][0];
        #pragma unroll
        for (int r = 1; r < 16; ++r) mx = fmaxf(mx, p[0][r]);
        #pragma unroll
        for (int r = 0; r < 16; ++r) mx = fmaxf(mx, p[1][r]);
        mx = fmaxf(mx, __shfl_xor(mx, 32));

        if (__any(mx > m_r + 8.f)) {           // defer-max: rescale only on real growth
            const float mn    = fmaxf(m_r, mx);
            const float alpha = __expf(m_r - mn);
            m_r  = mn;
            l_r *= alpha;
            #pragma unroll
            for (int r = 0; r < 16; ++r) {
                const float ab = __shfl(alpha, (r & 3) + 8 * (r >> 2) + 4 * hi);
                o0[r] *= ab; o1[r] *= ab;
            }
        }

        float rs = 0.f;
        #pragma unroll
        for (int r = 0; r < 16; ++r) { p[0][r] = __expf(p[0][r] - m_r); rs += p[0][r]; }
        #pragma unroll
        for (int r = 0; r < 16; ++r) { p[1][r] = __expf(p[1][r] - m_r); rs += p[1][r]; }
        rs += __shfl_xor(rs, 32);
        l_r += rs;

        // ---- P -> A-fragments (in-register, cross-half exchange) ----
        bf16x8 pa[4];
        #pragma unroll
        for (int kc = 0; kc < 4; ++kc) {
            const int kb = kc >> 1, bs = (kc & 1) * 8;
            const unsigned w01 = pk2(p[kb][bs + 0], p[kb][bs + 1]);
            const unsigned w23 = pk2(p[kb][bs + 2], p[kb][bs + 3]);
            const unsigned w45 = pk2(p[kb][bs + 4], p[kb][bs + 5]);
            const unsigned w67 = pk2(p[kb][bs + 6], p[kb][bs + 7]);
            const unsigned x01 = (unsigned)__shfl_xor((int)w01, 32);
            const unsigned x23 = (unsigned)__shfl_xor((int)w23, 32);
            const unsigned x45 = (unsigned)__shfl_xor((int)w45, 32);
            const unsigned x67 = (unsigned)__shfl_xor((int)w67, 32);
            U4S8 t;
            t.u = make_uint4(hi ? x45 : w01, hi ? x67 : w23,
                             hi ? w45 : x01, hi ? w67 : x23);
            pa[kc] = t.s;
        }

        // ---- O += P V ----
        #pragma unroll
        for (int kc = 0; kc < 4; ++kc) {
            U4S8 tv0; tv0.u = sV4[cur][kc * 2][lane];
            o0 = __builtin_amdgcn_mfma_f32_32x32x16_bf16(pa[kc], tv0.s, o0, 0, 0, 0);
            U4S8 tv1; tv1.u = sV4[cur][kc * 2 + 1][lane];
            o1 = __builtin_amdgcn_mfma_f32_32x32x16_bf16(pa[kc], tv1.s, o1, 0, 0, 0);
        }

        if (pf) write_tile(cur ^ 1);   // late ds_write (loads have drained under compute)
        __syncthreads();
    }

    // ---- epilogue: normalize and store (rows = crow layout) ----
    const float linv = 1.f / l_r;
    float* Op = Og + base;
    #pragma unroll
    for (int r = 0; r < 16; ++r) {
        const int   cr  = (r & 3) + 8 * (r >> 2) + 4 * hi;
        const float lb  = __shfl(linv, cr);
        const int   row = q0 + cr;
        Op[(size_t)row * DHEAD + c]      = o0[r] * lb;
        Op[(size_t)row * DHEAD + 32 + c] = o1[r] * lb;
    }
}

extern "C" void kernel_launch(void* const* d_in, const int* in_sizes, int n_in,
                              void* d_out, int out_size, void* d_ws, size_t ws_size,
                              hipStream_t stream) {
    const float* Q = (const float*)d_in[0];
    const float* K = (const float*)d_in[1];
    const float* V = (const float*)d_in[2];
    float* O = (float*)d_out;
    fattn_kernel<<<dim3(1024), dim3(128), 0, stream>>>(Q, K, V, O);
}

// Round 3
// 75.774 us; speedup vs baseline: 1.7838x; 1.0454x over previous
//
#include <hip/hip_runtime.h>
#include <hip/hip_bf16.h>

typedef __attribute__((ext_vector_type(8))) short bf16x8;
typedef __attribute__((ext_vector_type(16))) float f32x16;

#define DHEAD 64
#define L_SEQ 2048
// softmax scale 1/8 folded with log2(e): softmax exp(x) == exp2(x*log2e)
#define QSCALE (0.125f * 1.44269504088896340736f)

union U4S8 { uint4 u; bf16x8 s; };

__device__ __forceinline__ unsigned pk2(float a, float b) {
    union { __hip_bfloat162 h; unsigned u; } v;
    v.h = __float22bfloat162_rn(make_float2(a, b));
    return v.u;
}

__device__ __forceinline__ float fexp2(float x) {
#if __has_builtin(__builtin_amdgcn_exp2f)
    return __builtin_amdgcn_exp2f(x);
#else
    return __expf(x * 0.69314718055994530942f);
#endif
}

// LDS layouts (per buffer, 8 chunks x 64 slots x 16B):
//  K chunk kb*4+kc, slot l: K[kb*32+(l&31)][kc*16+8*(l>>5)+j], j=0..7   (A-frag order)
//  V chunk kc*2+dt, slot l: V[kc*16+8*(l>>5)+j][dt*32+(l&31)], j=0..7   (B-frag order)
// All ds_read AND ds_write are chunk_base + lane*16B => conflict-free by construction.

__global__ __launch_bounds__(256, 2)
void fattn_kernel(const float* __restrict__ Qg, const float* __restrict__ Kg,
                  const float* __restrict__ Vg, float* __restrict__ Og) {
    __shared__ uint4 sK4[2][8][64];
    __shared__ uint4 sV4[2][8][64];

    const int tid  = threadIdx.x;
    const int lane = tid & 63;
    const int w    = tid >> 6;     // wave -> its own 32-row q-tile
    const int hi   = lane >> 5;
    const int c    = lane & 31;

    // Block decode: 512 blocks = 32 bh x 16 T. XCD-group 4 bh per XCD (K/V set ~ L2),
    // heavy/light T pairing for load balance.
    const int id  = blockIdx.x;
    const int xcd = id & 7;
    const int s_  = id >> 3;              // 0..63
    const int bh  = xcd + 8 * (s_ & 3);   // 4 bh per XCD
    const int u_  = s_ >> 2;              // 0..15
    const int T   = (u_ & 1) ? (15 - (u_ >> 1)) : (u_ >> 1);

    const size_t base = (size_t)bh * L_SEQ * DHEAD;
    const int nt    = 2 * T + 2;          // KV tiles this block runs
    const int q0w   = T * 128 + w * 32;   // this wave's q rows
    const int ktmax = (q0w + 31) >> 6;    // last KV tile this wave needs

    // ---- Q fragments (B-operand), scale folded ----
    bf16x8 qf[4];
    {
        const float* Qrow = Qg + base + (size_t)(q0w + c) * DHEAD;
        #pragma unroll
        for (int kc = 0; kc < 4; ++kc) {
            float4 aa = *(const float4*)(Qrow + kc * 16 + hi * 8);
            float4 bb = *(const float4*)(Qrow + kc * 16 + hi * 8 + 4);
            U4S8 t;
            t.u = make_uint4(pk2(aa.x * QSCALE, aa.y * QSCALE),
                             pk2(aa.z * QSCALE, aa.w * QSCALE),
                             pk2(bb.x * QSCALE, bb.y * QSCALE),
                             pk2(bb.z * QSCALE, bb.w * QSCALE));
            qf[kc] = t.s;
        }
    }

    // ---- staging addresses (wave w owns chunks 2w, 2w+1 of both K and V) ----
    const int krow  = (w >> 1) * 32 + c;          // K row within tile
    const int kcol0 = (w & 1) * 32 + hi * 8;      // K col base (chunk 2w)
    const int vrow  = w * 16 + hi * 8;            // V row base
    const float* Kpb = Kg + base + (size_t)krow * DHEAD + kcol0;
    const float* Vpb = Vg + base + (size_t)vrow * DHEAD + c;

    float4 rk[4];
    float  rv[16];

    auto load_tile = [&](int kt) {
        const float* Kp = Kpb + (size_t)kt * 64 * DHEAD;
        rk[0] = *(const float4*)(Kp + 0);
        rk[1] = *(const float4*)(Kp + 4);
        rk[2] = *(const float4*)(Kp + 16);
        rk[3] = *(const float4*)(Kp + 20);
        const float* Vp = Vpb + (size_t)kt * 64 * DHEAD;
        #pragma unroll
        for (int j = 0; j < 8; ++j) {
            rv[j]     = Vp[j * DHEAD];
            rv[8 + j] = Vp[j * DHEAD + 32];
        }
    };

    auto write_tile = [&](int nb) {
        sK4[nb][2 * w][lane]     = make_uint4(pk2(rk[0].x, rk[0].y), pk2(rk[0].z, rk[0].w),
                                              pk2(rk[1].x, rk[1].y), pk2(rk[1].z, rk[1].w));
        sK4[nb][2 * w + 1][lane] = make_uint4(pk2(rk[2].x, rk[2].y), pk2(rk[2].z, rk[2].w),
                                              pk2(rk[3].x, rk[3].y), pk2(rk[3].z, rk[3].w));
        sV4[nb][2 * w][lane]     = make_uint4(pk2(rv[0], rv[1]),  pk2(rv[2], rv[3]),
                                              pk2(rv[4], rv[5]),  pk2(rv[6], rv[7]));
        sV4[nb][2 * w + 1][lane] = make_uint4(pk2(rv[8], rv[9]),  pk2(rv[10], rv[11]),
                                              pk2(rv[12], rv[13]), pk2(rv[14], rv[15]));
    };

    f32x16 o0 = {0,0,0,0,0,0,0,0,0,0,0,0,0,0,0,0};
    f32x16 o1 = {0,0,0,0,0,0,0,0,0,0,0,0,0,0,0,0};
    float m_r = -1e30f, l_r = 0.f;

    load_tile(0);
    write_tile(0);
    __syncthreads();

    for (int kt = 0; kt < nt; ++kt) {
        const int  cur = kt & 1;
        const bool pf  = (kt + 1 < nt);
        if (pf) load_tile(kt + 1);          // issue-early: hides under compute (T14)

        if (kt <= ktmax) {
            // full1: keys 32..63 of this tile are entirely above this wave's causal line
            const bool full1 = (64 * kt + 32 > q0w + 31);

            // ---- S^T = K * Q^T ----
            f32x16 s0 = {0,0,0,0,0,0,0,0,0,0,0,0,0,0,0,0};
            f32x16 s1 = {0,0,0,0,0,0,0,0,0,0,0,0,0,0,0,0};
            __builtin_amdgcn_s_setprio(1);
            #pragma unroll
            for (int kc = 0; kc < 4; ++kc) {
                U4S8 t0; t0.u = sK4[cur][kc][lane];
                s0 = __builtin_amdgcn_mfma_f32_32x32x16_bf16(t0.s, qf[kc], s0, 0, 0, 0);
            }
            if (!full1) {
                #pragma unroll
                for (int kc = 0; kc < 4; ++kc) {
                    U4S8 t1; t1.u = sK4[cur][4 + kc][lane];
                    s1 = __builtin_amdgcn_mfma_f32_32x32x16_bf16(t1.s, qf[kc], s1, 0, 0, 0);
                }
            }
            __builtin_amdgcn_s_setprio(0);

            float p[2][16];
            #pragma unroll
            for (int r = 0; r < 16; ++r) { p[0][r] = s0[r]; p[1][r] = full1 ? -1e30f : s1[r]; }

            if (kt == ktmax) {              // diagonal tile: causal mask
                const int qrel = q0w + c - 64 * kt;
                #pragma unroll
                for (int r = 0; r < 16; ++r) {
                    const int kk = (r & 3) + 8 * (r >> 2) + 4 * hi;
                    if (kk > qrel)      p[0][r] = -1e30f;
                    if (kk + 32 > qrel) p[1][r] = -1e30f;
                }
            }

            // ---- online softmax (exp2 domain), q = q0w + c ----
            float mx = p[0][0];
            #pragma unroll
            for (int r = 1; r < 16; ++r) mx = fmaxf(mx, p[0][r]);
            if (!full1) {
                #pragma unroll
                for (int r = 0; r < 16; ++r) mx = fmaxf(mx, p[1][r]);
            }
            mx = fmaxf(mx, __shfl_xor(mx, 32));

            if (__any(mx > m_r + 8.f)) {    // defer-max (T13)
                const float mn    = fmaxf(m_r, mx);
                const float alpha = fexp2(m_r - mn);
                m_r  = mn;
                l_r *= alpha;
                #pragma unroll
                for (int r = 0; r < 16; ++r) {
                    const float ab = __shfl(alpha, (r & 3) + 8 * (r >> 2) + 4 * hi);
                    o0[r] *= ab; o1[r] *= ab;
                }
            }

            float rs = 0.f;
            #pragma unroll
            for (int r = 0; r < 16; ++r) { p[0][r] = fexp2(p[0][r] - m_r); rs += p[0][r]; }
            if (!full1) {
                #pragma unroll
                for (int r = 0; r < 16; ++r) { p[1][r] = fexp2(p[1][r] - m_r); rs += p[1][r]; }
            }
            rs += __shfl_xor(rs, 32);
            l_r += rs;

            // ---- P -> A-fragments (in-register cross-half exchange) ----
            bf16x8 pa[4];
            const int npa = full1 ? 2 : 4;
            #pragma unroll
            for (int kc = 0; kc < 4; ++kc) {
                if (kc >= npa) break;
                const int kb = kc >> 1, bs = (kc & 1) * 8;
                const unsigned w01 = pk2(p[kb][bs + 0], p[kb][bs + 1]);
                const unsigned w23 = pk2(p[kb][bs + 2], p[kb][bs + 3]);
                const unsigned w45 = pk2(p[kb][bs + 4], p[kb][bs + 5]);
                const unsigned w67 = pk2(p[kb][bs + 6], p[kb][bs + 7]);
                const unsigned x01 = (unsigned)__shfl_xor((int)w01, 32);
                const unsigned x23 = (unsigned)__shfl_xor((int)w23, 32);
                const unsigned x45 = (unsigned)__shfl_xor((int)w45, 32);
                const unsigned x67 = (unsigned)__shfl_xor((int)w67, 32);
                U4S8 t;
                t.u = make_uint4(hi ? x45 : w01, hi ? x67 : w23,
                                 hi ? w45 : x01, hi ? w67 : x23);
                pa[kc] = t.s;
            }

            // ---- O += P V ----
            __builtin_amdgcn_s_setprio(1);
            #pragma unroll
            for (int kc = 0; kc < 4; ++kc) {
                if (kc >= npa) break;
                U4S8 tv0; tv0.u = sV4[cur][kc * 2][lane];
                o0 = __builtin_amdgcn_mfma_f32_32x32x16_bf16(pa[kc], tv0.s, o0, 0, 0, 0);
                U4S8 tv1; tv1.u = sV4[cur][kc * 2 + 1][lane];
                o1 = __builtin_amdgcn_mfma_f32_32x32x16_bf16(pa[kc], tv1.s, o1, 0, 0, 0);
            }
            __builtin_amdgcn_s_setprio(0);
        }

        if (pf) write_tile(cur ^ 1);        // write-late (loads drained under compute)
        __syncthreads();
    }

    // ---- epilogue: normalize and store ----
    const float linv = 1.f / l_r;
    float* Op = Og + base;
    #pragma unroll
    for (int r = 0; r < 16; ++r) {
        const int   cr  = (r & 3) + 8 * (r >> 2) + 4 * hi;
        const float lb  = __shfl(linv, cr);
        const int   row = q0w + cr;
        Op[(size_t)row * DHEAD + c]      = o0[r] * lb;
        Op[(size_t)row * DHEAD + 32 + c] = o1[r] * lb;
    }
}

extern "C" void kernel_launch(void* const* d_in, const int* in_sizes, int n_in,
                              void* d_out, int out_size, void* d_ws, size_t ws_size,
                              hipStream_t stream) {
    const float* Q = (const float*)d_in[0];
    const float* K = (const float*)d_in[1];
    const float* V = (const float*)d_in[2];
    float* O = (float*)d_out;
    fattn_kernel<<<dim3(512), dim3(256), 0, stream>>>(Q, K, V, O);
}

// Round 4
// 69.845 us; speedup vs baseline: 1.9353x; 1.0849x over previous
//
#include <hip/hip_runtime.h>
#include <hip/hip_bf16.h>

typedef __attribute__((ext_vector_type(8))) short bf16x8;
typedef __attribute__((ext_vector_type(16))) float f32x16;

#define DHEAD 64
#define L_SEQ 2048
// softmax scale 1/8 folded with log2(e): exp(x/8) == exp2(x*QSCALE)
#define QSCALE (0.125f * 1.44269504088896340736f)

union U4S8 { uint4 u; bf16x8 s; };

__device__ __forceinline__ unsigned pk2(float a, float b) {
    union { __hip_bfloat162 h; unsigned u; } v;
    v.h = __float22bfloat162_rn(make_float2(a, b));
    return v.u;
}

__device__ __forceinline__ float fexp2(float x) {
#if __has_builtin(__builtin_amdgcn_exp2f)
    return __builtin_amdgcn_exp2f(x);
#else
    return __expf(x * 0.69314718055994530942f);
#endif
}

// LDS layouts (per buffer, 16 chunks x 64 slots x 16B = 16KB each for K and V):
//  K chunk kb*4+kc, slot l: K[kb*32+(l&31)][kc*16+8*(l>>5)+j], j=0..7   (A-frag order)
//  V chunk kc*2+dt, slot l: V[kc*16+8*(l>>5)+j][dt*32+(l&31)], j=0..7   (B-frag order)
// Every ds_read AND ds_write is chunk_base + lane*16B => conflict-free by construction.

__global__ __launch_bounds__(256, 2)
void fattn_kernel(const float* __restrict__ Qg, const float* __restrict__ Kg,
                  const float* __restrict__ Vg, float* __restrict__ Og) {
    __shared__ uint4 sK4[2][16][64];
    __shared__ uint4 sV4[2][16][64];

    const int tid  = threadIdx.x;
    const int lane = tid & 63;
    const int w    = tid >> 6;     // wave -> its own 32-row q-tile
    const int hi   = lane >> 5;
    const int c    = lane & 31;

    // Block decode: 512 blocks = 32 bh x 16 T.
    //  - bh(i) == bh(i+256) and T(i)+T(i+256) == 15  => co-resident pair on a CU is
    //    work-balanced AND shares the head (L2 locality).
    //  - heavy T first (LPT).  XCD grouping: 4 bh per XCD.
    const int id  = blockIdx.x;
    const int bh  = (id & 7) + 8 * ((id >> 3) & 3);
    const int u_  = id >> 5;                       // 0..15
    const int T   = (u_ < 8) ? (15 - u_) : (u_ - 8);

    const size_t base = (size_t)bh * L_SEQ * DHEAD;
    const int nt  = T + 1;               // 128-key KV tiles
    const int q0w = T * 128 + w * 32;    // this wave's q rows

    // ---- Q fragments (B-operand), scale folded ----
    bf16x8 qf[4];
    {
        const float* Qrow = Qg + base + (size_t)(q0w + c) * DHEAD;
        #pragma unroll
        for (int kc = 0; kc < 4; ++kc) {
            float4 aa = *(const float4*)(Qrow + kc * 16 + hi * 8);
            float4 bb = *(const float4*)(Qrow + kc * 16 + hi * 8 + 4);
            U4S8 t;
            t.u = make_uint4(pk2(aa.x * QSCALE, aa.y * QSCALE),
                             pk2(aa.z * QSCALE, aa.w * QSCALE),
                             pk2(bb.x * QSCALE, bb.y * QSCALE),
                             pk2(bb.z * QSCALE, bb.w * QSCALE));
            qf[kc] = t.s;
        }
    }

    // ---- staging: thread (w,hi,c) ----
    //  K: row 32w+c, cols [32hi, 32hi+32)  -> 8x dwordx4
    //  V: rows [32w+16hi, +16), cols {c, c+32} -> 32x dword (128B coalesced/wave)
    const float* Kpb = Kg + base + (size_t)(32 * w + c) * DHEAD + 32 * hi;
    const float* Vpb = Vg + base + (size_t)(32 * w + 16 * hi) * DHEAD + c;

    float4 rk[8];
    float  rv[32];

    auto load_tile = [&](int kt) {
        const float* Kp = Kpb + (size_t)kt * 128 * DHEAD;
        #pragma unroll
        for (int t = 0; t < 8; ++t) rk[t] = *(const float4*)(Kp + 4 * t);
        const float* Vp = Vpb + (size_t)kt * 128 * DHEAD;
        #pragma unroll
        for (int j = 0; j < 16; ++j) {
            rv[j]      = Vp[j * DHEAD];
            rv[16 + j] = Vp[j * DHEAD + 32];
        }
    };

    auto write_tile = [&](int nb) {
        #pragma unroll
        for (int q = 0; q < 2; ++q)
            #pragma unroll
            for (int h = 0; h < 2; ++h) {
                const float4 r0 = rk[4 * q + 2 * h], r1 = rk[4 * q + 2 * h + 1];
                sK4[nb][w * 4 + 2 * hi + q][h * 32 + c] =
                    make_uint4(pk2(r0.x, r0.y), pk2(r0.z, r0.w),
                               pk2(r1.x, r1.y), pk2(r1.z, r1.w));
            }
        #pragma unroll
        for (int dt = 0; dt < 2; ++dt)
            #pragma unroll
            for (int h = 0; h < 2; ++h) {
                const int b = 16 * dt + 8 * h;
                sV4[nb][(2 * w + hi) * 2 + dt][h * 32 + c] =
                    make_uint4(pk2(rv[b + 0], rv[b + 1]), pk2(rv[b + 2], rv[b + 3]),
                               pk2(rv[b + 4], rv[b + 5]), pk2(rv[b + 6], rv[b + 7]));
            }
    };

    f32x16 o0 = {0,0,0,0,0,0,0,0,0,0,0,0,0,0,0,0};
    f32x16 o1 = {0,0,0,0,0,0,0,0,0,0,0,0,0,0,0,0};
    float m_r = -1e30f, l_r = 0.f;

    load_tile(0);
    write_tile(0);
    __syncthreads();

    for (int kt = 0; kt < nt; ++kt) {
        const int  cur = kt & 1;
        const bool pf  = (kt + 1 < nt);
        if (pf) load_tile(kt + 1);          // issue-early (T14): hides under compute

        const bool diag = (kt == T);
        const int  nkb  = diag ? (w + 1) : 4;   // live 32-key sub-blocks this wave

        float p[4][16];

        // ---- S^T = K * Q^T ----
        __builtin_amdgcn_s_setprio(1);
        #pragma unroll
        for (int kb = 0; kb < 4; ++kb) {
            if (kb < nkb) {
                f32x16 s = {0,0,0,0,0,0,0,0,0,0,0,0,0,0,0,0};
                #pragma unroll
                for (int kc = 0; kc < 4; ++kc) {
                    U4S8 t; t.u = sK4[cur][kb * 4 + kc][lane];
                    s = __builtin_amdgcn_mfma_f32_32x32x16_bf16(t.s, qf[kc], s, 0, 0, 0);
                }
                #pragma unroll
                for (int r = 0; r < 16; ++r) p[kb][r] = s[r];
            }
        }
        __builtin_amdgcn_s_setprio(0);

        if (diag) {     // mask only this wave's own diagonal 32x32 (kb == w)
            #pragma unroll
            for (int kb = 0; kb < 4; ++kb) {
                if (kb == w) {
                    #pragma unroll
                    for (int r = 0; r < 16; ++r) {
                        const int kk = (r & 3) + 8 * (r >> 2) + 4 * hi;
                        if (kk > c) p[kb][r] = -1e30f;
                    }
                }
            }
        }

        // ---- online softmax over up to 128 keys (exp2 domain) ----
        float mx = -1e30f;
        #pragma unroll
        for (int kb = 0; kb < 4; ++kb) {
            if (kb < nkb) {
                #pragma unroll
                for (int r = 0; r < 16; ++r) mx = fmaxf(mx, p[kb][r]);
            }
        }
        mx = fmaxf(mx, __shfl_xor(mx, 32));

        if (__any(mx > m_r + 8.f)) {        // defer-max (T13)
            const float mn    = fmaxf(m_r, mx);
            const float alpha = fexp2(m_r - mn);
            m_r  = mn;
            l_r *= alpha;
            #pragma unroll
            for (int r = 0; r < 16; ++r) {
                const float ab = __shfl(alpha, (r & 3) + 8 * (r >> 2) + 4 * hi);
                o0[r] *= ab; o1[r] *= ab;
            }
        }

        float rs = 0.f;
        #pragma unroll
        for (int kb = 0; kb < 4; ++kb) {
            if (kb < nkb) {
                #pragma unroll
                for (int r = 0; r < 16; ++r) { p[kb][r] = fexp2(p[kb][r] - m_r); rs += p[kb][r]; }
            }
        }
        rs += __shfl_xor(rs, 32);
        l_r += rs;

        // ---- P -> A-frags (in-register cross-half exchange) + O += P V ----
        __builtin_amdgcn_s_setprio(1);
        #pragma unroll
        for (int kc = 0; kc < 8; ++kc) {
            if (kc < 2 * nkb) {
                const int kb = kc >> 1, bs = (kc & 1) * 8;
                const unsigned w01 = pk2(p[kb][bs + 0], p[kb][bs + 1]);
                const unsigned w23 = pk2(p[kb][bs + 2], p[kb][bs + 3]);
                const unsigned w45 = pk2(p[kb][bs + 4], p[kb][bs + 5]);
                const unsigned w67 = pk2(p[kb][bs + 6], p[kb][bs + 7]);
                const unsigned x01 = (unsigned)__shfl_xor((int)w01, 32);
                const unsigned x23 = (unsigned)__shfl_xor((int)w23, 32);
                const unsigned x45 = (unsigned)__shfl_xor((int)w45, 32);
                const unsigned x67 = (unsigned)__shfl_xor((int)w67, 32);
                U4S8 t;
                t.u = make_uint4(hi ? x45 : w01, hi ? x67 : w23,
                                 hi ? w45 : x01, hi ? w67 : x23);
                U4S8 tv0; tv0.u = sV4[cur][kc * 2][lane];
                o0 = __builtin_amdgcn_mfma_f32_32x32x16_bf16(t.s, tv0.s, o0, 0, 0, 0);
                U4S8 tv1; tv1.u = sV4[cur][kc * 2 + 1][lane];
                o1 = __builtin_amdgcn_mfma_f32_32x32x16_bf16(t.s, tv1.s, o1, 0, 0, 0);
            }
        }
        __builtin_amdgcn_s_setprio(0);

        if (pf) write_tile(cur ^ 1);        // write-late (loads drained under compute)
        __syncthreads();
    }

    // ---- epilogue: normalize and store ----
    const float linv = 1.f / l_r;
    float* Op = Og + base;
    #pragma unroll
    for (int r = 0; r < 16; ++r) {
        const int   cr  = (r & 3) + 8 * (r >> 2) + 4 * hi;
        const float lb  = __shfl(linv, cr);
        const int   row = q0w + cr;
        Op[(size_t)row * DHEAD + c]      = o0[r] * lb;
        Op[(size_t)row * DHEAD + 32 + c] = o1[r] * lb;
    }
}

extern "C" void kernel_launch(void* const* d_in, const int* in_sizes, int n_in,
                              void* d_out, int out_size, void* d_ws, size_t ws_size,
                              hipStream_t stream) {
    const float* Q = (const float*)d_in[0];
    const float* K = (const float*)d_in[1];
    const float* V = (const float*)d_in[2];
    float* O = (float*)d_out;
    fattn_kernel<<<dim3(512), dim3(256), 0, stream>>>(Q, K, V, O);
}